// Round 2
// baseline (603.510 us; speedup 1.0000x reference)
//
#include <hip/hip_runtime.h>

// EntityAwareLSTMLayer: B=1024, T=365, DYN=32, STATIC=27, U=256 (3U=768)
// Round 6: attack the LDS pipe (the measured wall at ~2,750 cy/step).
//   - Dedup A rows at READ time: A_s rows = 4 real batch rows; MFMA A-row
//     (lane&15) reads A_s[mm&3] -> same-address broadcast across quads (free).
//     h written ONCE per cell (2 b16/thread, was 8); x staged by 128 thr.
//   - AP 296 -> 288: row stride 144 dwords == 16 mod 32 -> rows alternate
//     bank halves {0,16}, every bank serves exactly 2 unique addrs = free
//     2-way (m136). Kills the 3-way A-read conflicts (2.69e7 counter).
//   - NREG 6 -> 7: only W_hh k-chunk 7 streamed from LDS (48KB tile);
//     streamed-B reads halve 96 -> 48 b128/CU/step.
//   - Register plan: 48 frags(192) + acc(24) + temps(~15) + state(~20) ~ 250
//     of 256 (2 waves/SIMD). Watch for spill regression.

typedef short short8 __attribute__((ext_vector_type(8)));
typedef float f32x4 __attribute__((ext_vector_type(4)));

#define T_STEPS 365
#define UNITS   256
#define G3      768
#define KTOT    288   // 256 (h) + 32 (x)
#define MROWS   4
#define NWGS    256
#define AP      288   // A row length in shorts (576 B = 144 dwords, ==16 mod 32)
#define NREG    7     // W_hh 32-k chunks resident in registers (ks 0..6)

__device__ __forceinline__ unsigned short f2bf(float x) {
    union { float f; unsigned u; } v; v.f = x;
    return (unsigned short)((v.u + 0x7FFFu + ((v.u >> 16) & 1u)) >> 16);
}
__device__ __forceinline__ float sigmoidf_(float x) {
    return 1.0f / (1.0f + __expf(-x));
}
__device__ __forceinline__ float tanhf_(float x) {
    return 1.0f - 2.0f / (1.0f + __expf(2.0f * x));
}
// pick element qq of a f32x4 with compile-time indices only (avoid scratch)
__device__ __forceinline__ float selq(f32x4 v, int qq) {
    const float a = (qq & 1) ? v[1] : v[0];
    const float b = (qq & 1) ? v[3] : v[2];
    return (qq & 2) ? b : a;
}
__device__ __forceinline__ f32x4 MF(short8 a, short8 b, f32x4 c) {
    return __builtin_amdgcn_mfma_f32_16x16x32_bf16(a, b, c, 0, 0, 0);
}

// Wpack[k=0..287][n=0..767] -> bf16 B-fragment layout:
//   element (k,n) at wp[((k>>3)*768 + n)*8 + (k&7)]
__global__ __launch_bounds__(256) void pack_weights(
    const float* __restrict__ w_ih, const float* __restrict__ w_hh,
    unsigned short* __restrict__ wp)
{
    int idx = blockIdx.x * 256 + threadIdx.x;
    if (idx >= KTOT * G3) return;
    int k = idx / G3, n = idx - k * G3;
    float v;
    if (k < UNITS) {
        v = w_hh[k * G3 + n];
        if ((n & 255) == k) v -= 1.0f;   // subtract eye3 tile (identity added in fp32)
    } else {
        v = w_ih[(k - UNITS) * G3 + n];
    }
    wp[(((k >> 3) * G3) + n) * 8 + (k & 7)] = f2bf(v);
}

__global__ __launch_bounds__(512, 2) void lstm_mfma(
    const float* __restrict__ x_dyn,   // [1024][365][32]
    const float* __restrict__ x_sta,   // [1024][27]
    const unsigned short* __restrict__ wp,  // packed bf16 [36][768][8]
    const float* __restrict__ w_sh,    // [27][256]
    const float* __restrict__ bias,    // [768]
    const float* __restrict__ bias_s,  // [256]
    float* __restrict__ out)           // [1024][256]
{
    __shared__ unsigned short A_s[2][MROWS][AP];   // 4,608 B, double-buffered
    __shared__ unsigned short Bs_s[4 * G3 * 8];    // 49,152 B: W_hh chunk 7 (k=224..255)

    const int tid  = threadIdx.x;
    const int b0   = blockIdx.x * MROWS;
    const int lane = tid & 63;
    const int wv   = tid >> 6;          // wave 0..7, owns units wv*32..+31
    const int mm   = lane & 15;
    const int qq   = lane >> 4;

    // ---- persistent B fragments: 42 (hh ks 0..6) + 6 (ih) = 48 frags = 192 regs ----
    short8 bw[NREG][3][2];
    #pragma unroll
    for (int ks = 0; ks < NREG; ++ks)
        #pragma unroll
        for (int g = 0; g < 3; ++g)
            #pragma unroll
            for (int h = 0; h < 2; ++h)
                bw[ks][g][h] = *(const short8*)(wp +
                    ((size_t)(ks * 4 + qq) * G3 + g * UNITS + wv * 32 + h * 16 + mm) * 8);
    short8 bwx[3][2];
    #pragma unroll
    for (int g = 0; g < 3; ++g)
        #pragma unroll
        for (int h = 0; h < 2; ++h)
            bwx[g][h] = *(const short8*)(wp +
                ((size_t)(32 + qq) * G3 + g * UNITS + wv * 32 + h * 16 + mm) * 8);

    // ---- stage streamed W_hh chunk 7 (k=224..255, sub-chunks 28..31) into LDS ----
    {
        const short8* src = (const short8*)(wp + (size_t)28 * G3 * 8);
        short8* dst = (short8*)Bs_s;
        for (int i = tid; i < 4 * G3; i += 512) dst[i] = src[i];
    }
    // zero both A buffers (h-region must be 0 at t=0)
    {
        int* az = (int*)A_s;
        for (int i = tid; i < 2 * MROWS * AP / 2; i += 512) az[i] = 0;
    }
    __syncthreads();

    // stage x_0 into A[0] rows 0..3, prefetch x_1 (128 threads: one (row, feature) each)
    float xr = 0.0f;
    if (tid < MROWS * 32) {
        const int row = tid >> 5, j = tid & 31;
        const size_t bi = (size_t)(b0 + row) * T_STEPS;
        A_s[0][row][UNITS + j] = f2bf(x_dyn[(bi + 0) * 32 + j]);
        xr = x_dyn[(bi + 1) * 32 + j];
    }

    // ---- cell mapping: lane (mm,qq) owns cells (batch row qq, units u0,u1) ----
    const int u0 = wv * 32 + mm;
    const int u1 = u0 + 16;

    const float bfv[2] = { bias[u0],             bias[u1] };
    const float bov[2] = { bias[UNITS + u0],     bias[UNITS + u1] };
    const float bgv[2] = { bias[2 * UNITS + u0], bias[2 * UNITS + u1] };

    float ig[2], cc[2], hp[2];
    #pragma unroll
    for (int h = 0; h < 2; ++h) {
        const int u = h ? u1 : u0;
        float s = bias_s[u];
        #pragma unroll
        for (int j = 0; j < 27; ++j)
            s += x_sta[(b0 + qq) * 27 + j] * w_sh[j * UNITS + u];
        ig[h] = sigmoidf_(s);
        cc[h] = 0.0f; hp[h] = 0.0f;
    }

    const int arow = (mm & 3);          // dedup: quads broadcast-read same 4 rows

    for (int t = 0; t < T_STEPS; ++t) {
        const int p = t & 1;
        __syncthreads();   // A[p] = [h_t | x_t] complete; A[p^1] free

        const unsigned short* Ap = &A_s[p][0][0];
        const int abase = arow * AP + qq * 8;

        f32x4 acf0 = {0.f,0.f,0.f,0.f}, aco0 = {0.f,0.f,0.f,0.f}, acg0 = {0.f,0.f,0.f,0.f};
        f32x4 acf1 = {0.f,0.f,0.f,0.f}, aco1 = {0.f,0.f,0.f,0.f}, acg1 = {0.f,0.f,0.f,0.f};

        // k-chunks 0..6: B in registers; each A frag read once, feeds 6 MFMAs
        #pragma unroll
        for (int ks = 0; ks < NREG; ++ks) {
            const short8 a = *(const short8*)(Ap + abase + ks * 32);
            acf0 = MF(a, bw[ks][0][0], acf0);  acf1 = MF(a, bw[ks][0][1], acf1);
            aco0 = MF(a, bw[ks][1][0], aco0);  aco1 = MF(a, bw[ks][1][1], aco1);
            acg0 = MF(a, bw[ks][2][0], acg0);  acg1 = MF(a, bw[ks][2][1], acg1);
        }
        // k-chunk 7: B streamed from LDS (short-lived frags)
        {
            const short8 a = *(const short8*)(Ap + abase + NREG * 32);
            const unsigned short* bp = Bs_s + ((size_t)qq * G3 + wv * 32 + mm) * 8;
            acf0 = MF(a, *(const short8*)(bp),                        acf0);
            acf1 = MF(a, *(const short8*)(bp + 16 * 8),               acf1);
            aco0 = MF(a, *(const short8*)(bp + (UNITS) * 8),          aco0);
            aco1 = MF(a, *(const short8*)(bp + (UNITS + 16) * 8),     aco1);
            acg0 = MF(a, *(const short8*)(bp + (2 * UNITS) * 8),      acg0);
            acg1 = MF(a, *(const short8*)(bp + (2 * UNITS + 16) * 8), acg1);
        }
        // x-contribution chunk (k=256..287), B in registers
        {
            const short8 a = *(const short8*)(Ap + abase + UNITS);
            acf0 = MF(a, bwx[0][0], acf0);  acf1 = MF(a, bwx[0][1], acf1);
            aco0 = MF(a, bwx[1][0], aco0);  aco1 = MF(a, bwx[1][1], aco1);
            acg0 = MF(a, bwx[2][0], acg0);  acg1 = MF(a, bwx[2][1], acg1);
        }

        // ---- cell updates: acc reg qq of each f32x4 IS this lane's cell ----
        #pragma unroll
        for (int h = 0; h < 2; ++h) {
            const float h0v = hp[h];   // exact fp32 identity term of W_hh
            const float gfv = selq(h ? acf1 : acf0, qq) + bfv[h] + h0v;
            const float gov = selq(h ? aco1 : aco0, qq) + bov[h] + h0v;
            const float ggv = selq(h ? acg1 : acg0, qq) + bgv[h] + h0v;
            const float f   = sigmoidf_(gfv);
            const float o   = sigmoidf_(gov);
            const float gt  = tanhf_(ggv);
            const float cn  = f * cc[h] + ig[h] * gt;
            cc[h] = cn;
            const float hn  = o * tanhf_(cn);
            hp[h] = hn;
            const unsigned short hb = f2bf(hn);
            const int u = h ? u1 : u0;
            A_s[p ^ 1][qq][u] = hb;    // single write per cell (no duplication)
        }

        // stage x_{t+1} into A[p^1] rows 0..3; prefetch x_{t+2}
        if (tid < MROWS * 32) {
            const int row = tid >> 5, j = tid & 31;
            A_s[p ^ 1][row][UNITS + j] = f2bf(xr);
            if (t + 2 < T_STEPS)
                xr = x_dyn[((size_t)(b0 + row) * T_STEPS + (t + 2)) * 32 + j];
        }
    }

    out[(size_t)(b0 + qq) * UNITS + u0] = hp[0];
    out[(size_t)(b0 + qq) * UNITS + u1] = hp[1];
}

extern "C" void kernel_launch(void* const* d_in, const int* in_sizes, int n_in,
                              void* d_out, int out_size, void* d_ws, size_t ws_size,
                              hipStream_t stream) {
    const float* x_dyn  = (const float*)d_in[0];
    const float* x_sta  = (const float*)d_in[1];
    const float* w_ih   = (const float*)d_in[2];
    const float* w_hh   = (const float*)d_in[3];
    const float* w_sh   = (const float*)d_in[4];
    const float* bias   = (const float*)d_in[5];
    const float* bias_s = (const float*)d_in[6];
    float* out = (float*)d_out;
    unsigned short* wp = (unsigned short*)d_ws;   // 288*768*2 = 442 KB scratch

    pack_weights<<<(KTOT * G3 + 255) / 256, 256, 0, stream>>>(w_ih, w_hh, wp);
    lstm_mfma<<<NWGS, 512, 0, stream>>>(x_dyn, x_sta, wp, w_sh, bias, bias_s, out);
}

// Round 3
// 572.610 us; speedup vs baseline: 1.0540x; 1.0540x over previous
//
#include <hip/hip_runtime.h>

// EntityAwareLSTMLayer: B=1024, T=365, DYN=32, STATIC=27, U=256 (3U=768)
// Round 7: remove global memory (and its barrier vmcnt-drain) from the loop.
//   Round-6 post-mortem: bank conflicts 2.69e7 -> 0 with NO time change, so
//   LDS was not the wall. Invariant suspect: per-step x prefetch global_load
//   issued right before __syncthreads -> s_waitcnt vmcnt(0) drains L3 latency
//   (~400-600 cy) on the critical path of EVERY step.
//   - Pre-stage the WG's whole x slice (4 rows x 365 x 32 bf16 = 93.4 KB)
//     into LDS once; loop reads x-frag directly (2-way banks = free).
//   - Loop now touches NO global memory; barrier drains only LDS writes.
//   - A-tile is h-only: [2][4][272] (stride 272 -> uniform 2-way = free).
//   - LDS total 146.9 KB (<160), still 1 WG/CU (= current occupancy).
//   - W_hh ks 0..6 + W_ih in regs/AGPRs (48 frags), ks 7 streamed from LDS.

typedef short short8 __attribute__((ext_vector_type(8)));
typedef short short4s __attribute__((ext_vector_type(4)));
typedef float f32x4 __attribute__((ext_vector_type(4)));

#define T_STEPS 365
#define UNITS   256
#define G3      768
#define KTOT    288   // 256 (h) + 32 (x)
#define MROWS   4
#define NWGS    256
#define HP      272   // h row stride in shorts (544 B; 136 dw == 8 mod 32 -> 2-way)
#define XROW    (T_STEPS * 32)   // 11,680 shorts per batch row
#define NREG    7     // W_hh 32-k chunks resident in registers (ks 0..6)

__device__ __forceinline__ unsigned short f2bf(float x) {
    union { float f; unsigned u; } v; v.f = x;
    return (unsigned short)((v.u + 0x7FFFu + ((v.u >> 16) & 1u)) >> 16);
}
__device__ __forceinline__ float sigmoidf_(float x) {
    return 1.0f / (1.0f + __expf(-x));
}
__device__ __forceinline__ float tanhf_(float x) {
    return 1.0f - 2.0f / (1.0f + __expf(2.0f * x));
}
// pick element qq of a f32x4 with compile-time indices only (avoid scratch)
__device__ __forceinline__ float selq(f32x4 v, int qq) {
    const float a = (qq & 1) ? v[1] : v[0];
    const float b = (qq & 1) ? v[3] : v[2];
    return (qq & 2) ? b : a;
}
__device__ __forceinline__ f32x4 MF(short8 a, short8 b, f32x4 c) {
    return __builtin_amdgcn_mfma_f32_16x16x32_bf16(a, b, c, 0, 0, 0);
}

// Wpack[k=0..287][n=0..767] -> bf16 B-fragment layout:
//   element (k,n) at wp[((k>>3)*768 + n)*8 + (k&7)]
__global__ __launch_bounds__(256) void pack_weights(
    const float* __restrict__ w_ih, const float* __restrict__ w_hh,
    unsigned short* __restrict__ wp)
{
    int idx = blockIdx.x * 256 + threadIdx.x;
    if (idx >= KTOT * G3) return;
    int k = idx / G3, n = idx - k * G3;
    float v;
    if (k < UNITS) {
        v = w_hh[k * G3 + n];
        if ((n & 255) == k) v -= 1.0f;   // subtract eye3 tile (identity added in fp32)
    } else {
        v = w_ih[(k - UNITS) * G3 + n];
    }
    wp[(((k >> 3) * G3) + n) * 8 + (k & 7)] = f2bf(v);
}

__global__ __launch_bounds__(512, 2) void lstm_mfma(
    const float* __restrict__ x_dyn,   // [1024][365][32]
    const float* __restrict__ x_sta,   // [1024][27]
    const unsigned short* __restrict__ wp,  // packed bf16 [36][768][8]
    const float* __restrict__ w_sh,    // [27][256]
    const float* __restrict__ bias,    // [768]
    const float* __restrict__ bias_s,  // [256]
    float* __restrict__ out)           // [1024][256]
{
    __shared__ unsigned short A_s[2][MROWS][HP];      //  4,352 B (h only, dbuf)
    __shared__ unsigned short xs[MROWS * XROW];       // 93,440 B (all x, bf16)
    __shared__ unsigned short Bs_s[4 * G3 * 8];       // 49,152 B (W_hh chunk 7)

    const int tid  = threadIdx.x;
    const int b0   = blockIdx.x * MROWS;
    const int lane = tid & 63;
    const int wv   = tid >> 6;          // wave 0..7, owns units wv*32..+31
    const int mm   = lane & 15;
    const int qq   = lane >> 4;

    // ---- persistent B fragments: 42 (hh ks 0..6) + 6 (ih) = 48 frags ----
    short8 bw[NREG][3][2];
    #pragma unroll
    for (int ks = 0; ks < NREG; ++ks)
        #pragma unroll
        for (int g = 0; g < 3; ++g)
            #pragma unroll
            for (int h = 0; h < 2; ++h)
                bw[ks][g][h] = *(const short8*)(wp +
                    ((size_t)(ks * 4 + qq) * G3 + g * UNITS + wv * 32 + h * 16 + mm) * 8);
    short8 bwx[3][2];
    #pragma unroll
    for (int g = 0; g < 3; ++g)
        #pragma unroll
        for (int h = 0; h < 2; ++h)
            bwx[g][h] = *(const short8*)(wp +
                ((size_t)(32 + qq) * G3 + g * UNITS + wv * 32 + h * 16 + mm) * 8);

    // ---- stage streamed W_hh chunk 7 (k=224..255, sub-chunks 28..31) ----
    {
        const short8* src = (const short8*)(wp + (size_t)28 * G3 * 8);
        short8* dst = (short8*)Bs_s;
        for (int i = tid; i < 4 * G3; i += 512) dst[i] = src[i];
    }
    // ---- pre-stage ALL x for this WG's 4 batch rows (fp32 -> bf16) ----
    #pragma unroll
    for (int r = 0; r < MROWS; ++r) {
        const float4* src = (const float4*)(x_dyn + (size_t)(b0 + r) * XROW);
        short4s* dst = (short4s*)(xs + r * XROW);
        for (int i = tid; i < XROW / 4; i += 512) {
            const float4 v = src[i];
            short4s w;
            w.x = (short)f2bf(v.x); w.y = (short)f2bf(v.y);
            w.z = (short)f2bf(v.z); w.w = (short)f2bf(v.w);
            dst[i] = w;
        }
    }
    // zero both h buffers (h must be 0 at t=0)
    {
        int* az = (int*)A_s;
        for (int i = tid; i < 2 * MROWS * HP / 2; i += 512) az[i] = 0;
    }
    __syncthreads();

    // ---- cell mapping: lane (mm,qq) owns cells (batch row qq, units u0,u1) ----
    const int u0 = wv * 32 + mm;
    const int u1 = u0 + 16;

    const float bfv[2] = { bias[u0],             bias[u1] };
    const float bov[2] = { bias[UNITS + u0],     bias[UNITS + u1] };
    const float bgv[2] = { bias[2 * UNITS + u0], bias[2 * UNITS + u1] };

    float ig[2], cc[2], hp[2];
    #pragma unroll
    for (int h = 0; h < 2; ++h) {
        const int u = h ? u1 : u0;
        float s = bias_s[u];
        #pragma unroll
        for (int j = 0; j < 27; ++j)
            s += x_sta[(b0 + qq) * 27 + j] * w_sh[j * UNITS + u];
        ig[h] = sigmoidf_(s);
        cc[h] = 0.0f; hp[h] = 0.0f;
    }

    const int arow = (mm & 3);          // dedup: quads broadcast-read same 4 rows
    const unsigned short* xp = xs + (size_t)arow * XROW + qq * 8;

    for (int t = 0; t < T_STEPS; ++t) {
        const int p = t & 1;
        __syncthreads();   // A[p] h complete; A[p^1] free. No vmem in flight.

        const unsigned short* Ap = &A_s[p][0][0];
        const int abase = arow * HP + qq * 8;

        f32x4 acf0 = {0.f,0.f,0.f,0.f}, aco0 = {0.f,0.f,0.f,0.f}, acg0 = {0.f,0.f,0.f,0.f};
        f32x4 acf1 = {0.f,0.f,0.f,0.f}, aco1 = {0.f,0.f,0.f,0.f}, acg1 = {0.f,0.f,0.f,0.f};

        // k-chunks 0..6: B in registers; each A frag read once, feeds 6 MFMAs
        #pragma unroll
        for (int ks = 0; ks < NREG; ++ks) {
            const short8 a = *(const short8*)(Ap + abase + ks * 32);
            acf0 = MF(a, bw[ks][0][0], acf0);  acf1 = MF(a, bw[ks][0][1], acf1);
            aco0 = MF(a, bw[ks][1][0], aco0);  aco1 = MF(a, bw[ks][1][1], aco1);
            acg0 = MF(a, bw[ks][2][0], acg0);  acg1 = MF(a, bw[ks][2][1], acg1);
        }
        // k-chunk 7: B streamed from LDS (short-lived frags)
        {
            const short8 a = *(const short8*)(Ap + abase + NREG * 32);
            const unsigned short* bp = Bs_s + ((size_t)qq * G3 + wv * 32 + mm) * 8;
            acf0 = MF(a, *(const short8*)(bp),                        acf0);
            acf1 = MF(a, *(const short8*)(bp + 16 * 8),               acf1);
            aco0 = MF(a, *(const short8*)(bp + (UNITS) * 8),          aco0);
            aco1 = MF(a, *(const short8*)(bp + (UNITS + 16) * 8),     aco1);
            acg0 = MF(a, *(const short8*)(bp + (2 * UNITS) * 8),      acg0);
            acg1 = MF(a, *(const short8*)(bp + (2 * UNITS + 16) * 8), acg1);
        }
        // x-contribution chunk (k=256..287): A from pre-staged x LDS tile
        {
            const short8 a = *(const short8*)(xp + t * 32);
            acf0 = MF(a, bwx[0][0], acf0);  acf1 = MF(a, bwx[0][1], acf1);
            aco0 = MF(a, bwx[1][0], aco0);  aco1 = MF(a, bwx[1][1], aco1);
            acg0 = MF(a, bwx[2][0], acg0);  acg1 = MF(a, bwx[2][1], acg1);
        }

        // ---- cell updates: acc reg qq of each f32x4 IS this lane's cell ----
        #pragma unroll
        for (int h = 0; h < 2; ++h) {
            const float h0v = hp[h];   // exact fp32 identity term of W_hh
            const float gfv = selq(h ? acf1 : acf0, qq) + bfv[h] + h0v;
            const float gov = selq(h ? aco1 : aco0, qq) + bov[h] + h0v;
            const float ggv = selq(h ? acg1 : acg0, qq) + bgv[h] + h0v;
            const float f   = sigmoidf_(gfv);
            const float o   = sigmoidf_(gov);
            const float gt  = tanhf_(ggv);
            const float cn  = f * cc[h] + ig[h] * gt;
            cc[h] = cn;
            const float hn  = o * tanhf_(cn);
            hp[h] = hn;
            A_s[p ^ 1][qq][h ? u1 : u0] = f2bf(hn);   // single b16 write per cell
        }
    }

    out[(size_t)(b0 + qq) * UNITS + u0] = hp[0];
    out[(size_t)(b0 + qq) * UNITS + u1] = hp[1];
}

extern "C" void kernel_launch(void* const* d_in, const int* in_sizes, int n_in,
                              void* d_out, int out_size, void* d_ws, size_t ws_size,
                              hipStream_t stream) {
    const float* x_dyn  = (const float*)d_in[0];
    const float* x_sta  = (const float*)d_in[1];
    const float* w_ih   = (const float*)d_in[2];
    const float* w_hh   = (const float*)d_in[3];
    const float* w_sh   = (const float*)d_in[4];
    const float* bias   = (const float*)d_in[5];
    const float* bias_s = (const float*)d_in[6];
    float* out = (float*)d_out;
    unsigned short* wp = (unsigned short*)d_ws;   // 288*768*2 = 442 KB scratch

    pack_weights<<<(KTOT * G3 + 255) / 256, 256, 0, stream>>>(w_ih, w_hh, wp);
    lstm_mfma<<<NWGS, 512, 0, stream>>>(x_dyn, x_sta, wp, w_sh, bias, bias_s, out);
}